// Round 1
// baseline (11.407 us; speedup 1.0000x reference)
//
#include <hip/hip_runtime.h>
#include <hip/hip_bf16.h>

// -sum_i( prob[i, target[i]] * reward[i] )
// N = 8192, C = 32000. prob: f32 (N,C), target: int (N,), reward: f32 (N,).
// Output: single f32 scalar.

__global__ void ganloss_partial(const float* __restrict__ prob,
                                const int* __restrict__ target,
                                const float* __restrict__ reward,
                                float* __restrict__ ws,
                                int N, int C) {
    int i = blockIdx.x * blockDim.x + threadIdx.x;
    float v = 0.0f;
    if (i < N) {
        int t = target[i];
        v = prob[(size_t)i * (size_t)C + (size_t)t] * reward[i];
    }
    // wave64 shuffle reduce
    #pragma unroll
    for (int off = 32; off > 0; off >>= 1)
        v += __shfl_down(v, off, 64);

    __shared__ float smem[4];  // 256 threads = 4 waves
    int lane = threadIdx.x & 63;
    int w    = threadIdx.x >> 6;
    if (lane == 0) smem[w] = v;
    __syncthreads();
    if (threadIdx.x == 0) {
        float s = smem[0] + smem[1] + smem[2] + smem[3];
        ws[blockIdx.x] = s;
    }
}

__global__ void ganloss_finalize(const float* __restrict__ ws,
                                 float* __restrict__ out,
                                 int nblocks) {
    // single wave of 64 threads
    float v = (threadIdx.x < nblocks) ? ws[threadIdx.x] : 0.0f;
    #pragma unroll
    for (int off = 32; off > 0; off >>= 1)
        v += __shfl_down(v, off, 64);
    if (threadIdx.x == 0) out[0] = -v;
}

extern "C" void kernel_launch(void* const* d_in, const int* in_sizes, int n_in,
                              void* d_out, int out_size, void* d_ws, size_t ws_size,
                              hipStream_t stream) {
    const float* prob   = (const float*)d_in[0];
    const int*   target = (const int*)d_in[1];
    const float* reward = (const float*)d_in[2];
    float* out = (float*)d_out;
    float* ws  = (float*)d_ws;

    const int N = in_sizes[1];      // 8192
    const int C = in_sizes[0] / N;  // 32000

    const int block = 256;
    const int nblocks = (N + block - 1) / block;  // 32

    ganloss_partial<<<nblocks, block, 0, stream>>>(prob, target, reward, ws, N, C);
    ganloss_finalize<<<1, 64, 0, stream>>>(ws, out, nblocks);
}